// Round 2
// baseline (725.010 us; speedup 1.0000x reference)
//
#include <hip/hip_runtime.h>
#include <hip/hip_bf16.h>

#define BB 2
#define SS 2048
#define EE 1024
#define HH 16
#define HD 64

typedef __attribute__((ext_vector_type(8))) __bf16 bf16x8;
typedef __attribute__((ext_vector_type(4))) __bf16 bf16x4;
typedef __attribute__((ext_vector_type(4))) float f32x4;

__device__ __forceinline__ void split2(float x, __bf16& h, __bf16& l) {
    h = (__bf16)x;                 // RTNE
    l = (__bf16)(x - (float)h);    // residual
}

// ---------------- K0: elementwise fp32 -> bf16 hi/lo split ----------------
__global__ __launch_bounds__(256) void k_split(const float* __restrict__ in,
                                               __bf16* __restrict__ hi,
                                               __bf16* __restrict__ lo, int n4)
{
    int i = blockIdx.x * 256 + threadIdx.x;
    if (i >= n4) return;
    const float4 v = *(const float4*)(in + (size_t)i * 4);
    float t[4] = {v.x, v.y, v.z, v.w};
    bf16x4 h4, l4;
#pragma unroll
    for (int e = 0; e < 4; ++e) {
        __bf16 h, l; split2(t[e], h, l);
        h4[e] = h; l4[e] = l;
    }
    *(bf16x4*)(hi + (size_t)i * 4) = h4;
    *(bf16x4*)(lo + (size_t)i * 4) = l4;
}

// ---------------- K1: QKV projection (split-bf16 GEMM, fp32-accurate) -----
// q and k' are emitted PRE-SPLIT as bf16 hi/lo; k' = k/8 + rel.
// v is emitted transposed bf16 [BH][HD][S].
__global__ __launch_bounds__(256) void k_qkv(
    const __bf16* __restrict__ xhi, const __bf16* __restrict__ xlo,
    const __bf16* __restrict__ whi, const __bf16* __restrict__ wlo,
    const float* __restrict__ bqkv, const float* __restrict__ rel,
    __bf16* __restrict__ qhi_ws, __bf16* __restrict__ qlo_ws,
    __bf16* __restrict__ khi_ws, __bf16* __restrict__ klo_ws,
    __bf16* __restrict__ vt_ws)
{
    __shared__ __bf16 Ahi[128][72], Alo[128][72];
    __shared__ __bf16 Bhi[64][72],  Blo[64][72];

    const int tid = threadIdx.x;
    const int lane = tid & 63;
    const int wv = tid >> 6;
    const int m0 = blockIdx.y * 128;
    const int f0 = blockIdx.x * 64;
    const int wr = (wv >> 1) * 64, wc = (wv & 1) * 32;
    const int lr = lane & 15, lg = lane >> 4;

    f32x4 acc[4][2];
#pragma unroll
    for (int a = 0; a < 4; ++a)
#pragma unroll
        for (int b = 0; b < 2; ++b) acc[a][b] = (f32x4){0.f, 0.f, 0.f, 0.f};

    for (int kt = 0; kt < 16; ++kt) {
        const int k0 = kt * 64;
        __syncthreads();
        {   // stage A tile 128x64 (hi+lo)
            const int c = tid & 7, r0 = tid >> 3;
#pragma unroll
            for (int i = 0; i < 4; ++i) {
                const int row = r0 + i * 32;
                const size_t g = (size_t)(m0 + row) * EE + k0 + c * 8;
                *(bf16x8*)&Ahi[row][c * 8] = *(const bf16x8*)(xhi + g);
                *(bf16x8*)&Alo[row][c * 8] = *(const bf16x8*)(xlo + g);
            }
        }
        {   // stage B tile 64x64 (hi+lo)
            const int c = tid & 7, r0 = tid >> 3;
#pragma unroll
            for (int i = 0; i < 2; ++i) {
                const int row = r0 + i * 32;
                const size_t g = (size_t)(f0 + row) * EE + k0 + c * 8;
                *(bf16x8*)&Bhi[row][c * 8] = *(const bf16x8*)(whi + g);
                *(bf16x8*)&Blo[row][c * 8] = *(const bf16x8*)(wlo + g);
            }
        }
        __syncthreads();
#pragma unroll
        for (int ks = 0; ks < 2; ++ks) {
            const int koff = ks * 32 + lg * 8;
            bf16x8 ah[4], al[4], bh[2], bl[2];
#pragma unroll
            for (int rt = 0; rt < 4; ++rt) {
                ah[rt] = *(const bf16x8*)&Ahi[wr + rt * 16 + lr][koff];
                al[rt] = *(const bf16x8*)&Alo[wr + rt * 16 + lr][koff];
            }
#pragma unroll
            for (int ct = 0; ct < 2; ++ct) {
                bh[ct] = *(const bf16x8*)&Bhi[wc + ct * 16 + lr][koff];
                bl[ct] = *(const bf16x8*)&Blo[wc + ct * 16 + lr][koff];
            }
#pragma unroll
            for (int rt = 0; rt < 4; ++rt)
#pragma unroll
                for (int ct = 0; ct < 2; ++ct) {
                    acc[rt][ct] = __builtin_amdgcn_mfma_f32_16x16x32_bf16(ah[rt], bh[ct], acc[rt][ct], 0, 0, 0);
                    acc[rt][ct] = __builtin_amdgcn_mfma_f32_16x16x32_bf16(al[rt], bh[ct], acc[rt][ct], 0, 0, 0);
                    acc[rt][ct] = __builtin_amdgcn_mfma_f32_16x16x32_bf16(ah[rt], bl[ct], acc[rt][ct], 0, 0, 0);
                }
        }
    }

    // epilogue: tile's 64 f-cols are one (h, q/k/v) block since f0 % 64 == 0
    const int blk = f0 >> 6;             // 0..47
    const int h = blk / 3, typ = blk % 3;
#pragma unroll
    for (int rt = 0; rt < 4; ++rt) {
        const int m = m0 + wr + rt * 16 + lg * 4;
        const int b = m >> 11, s = m & 2047;
#pragma unroll
        for (int ct = 0; ct < 2; ++ct) {
            const int d = wc + ct * 16 + lr;
            const float bq = bqkv[f0 + d];
            if (typ == 0) {
                const size_t base = ((size_t)(b * HH + h) * SS + s) * HD + d;
#pragma unroll
                for (int r = 0; r < 4; ++r) {
                    __bf16 hh, ll; split2(acc[rt][ct][r] + bq, hh, ll);
                    qhi_ws[base + (size_t)r * HD] = hh;
                    qlo_ws[base + (size_t)r * HD] = ll;
                }
            } else if (typ == 1) {
                const size_t base = ((size_t)(b * HH + h) * SS + s) * HD + d;
                const size_t rb = ((size_t)h * SS + s) * HD + d;
#pragma unroll
                for (int r = 0; r < 4; ++r) {
                    const float t = (acc[rt][ct][r] + bq) * 0.125f + rel[rb + (size_t)r * HD];
                    __bf16 hh, ll; split2(t, hh, ll);
                    khi_ws[base + (size_t)r * HD] = hh;
                    klo_ws[base + (size_t)r * HD] = ll;
                }
            } else {
                const size_t base = ((size_t)(b * HH + h) * HD + d) * SS + s;
                bf16x4 pk;
#pragma unroll
                for (int r = 0; r < 4; ++r) pk[r] = (__bf16)(acc[rt][ct][r] + bq);
                *(bf16x4*)&vt_ws[base] = pk;
            }
        }
    }
}

// ---------------- K2: fused two-pass attention ----------------------------
// Pass 1 (no barriers, no LDS): Z[i] = sum_j exp(q_i . k'_j), K-frags direct
// from global. Pass 2: recompute logits, weights = exp * (1/Z) streamed to
// global from registers; normalized P bounced through a tiny double-buffered
// LDS tile for the PV MFMA (B-operand v^T direct from global).
__global__ __launch_bounds__(512, 4) void k_attn2(
    const __bf16* __restrict__ qhi_ws, const __bf16* __restrict__ qlo_ws,
    const __bf16* __restrict__ khi_ws, const __bf16* __restrict__ klo_ws,
    const __bf16* __restrict__ vt_ws,
    float* __restrict__ wts, __bf16* __restrict__ av_ws)
{
    __shared__ __bf16 UT[2][32][72];   // normalized P tile, +8 pad
    __shared__ float ZB[32];

    const int tid = threadIdx.x;
    const int lane = tid & 63;
    const int wv = tid >> 6;          // 8 waves
    const int rg = wv >> 2, cw = wv & 3;
    const int lr = lane & 15, lg = lane >> 4;

    const int ib = blockIdx.x & 63;
    const int bh = blockIdx.x >> 6;
    const int i0 = ib * 32;
    const size_t kvbase = (size_t)bh * SS * HD;

    if (tid < 32) ZB[tid] = 0.f;
    __syncthreads();

    // q fragments (hi/lo), loaded once
    const __bf16* qh = qhi_ws + kvbase + (size_t)(i0 + rg * 16 + lr) * HD;
    const __bf16* ql = qlo_ws + kvbase + (size_t)(i0 + rg * 16 + lr) * HD;
    const bf16x8 qh0 = *(const bf16x8*)(qh + lg * 8);
    const bf16x8 qh1 = *(const bf16x8*)(qh + 32 + lg * 8);
    const bf16x8 ql0 = *(const bf16x8*)(ql + lg * 8);
    const bf16x8 ql1 = *(const bf16x8*)(ql + 32 + lg * 8);

    const __bf16* kh_base = khi_ws + kvbase + (size_t)(cw * 16 + lr) * HD + lg * 8;
    const __bf16* kl_base = klo_ws + kvbase + (size_t)(cw * 16 + lr) * HD + lg * 8;

    // ---- pass 1: Z ----
    float z4[4] = {0.f, 0.f, 0.f, 0.f};
#pragma unroll 2
    for (int jt = 0; jt < 32; ++jt) {
        const __bf16* kh = kh_base + (size_t)jt * (64 * HD);
        const __bf16* kl = kl_base + (size_t)jt * (64 * HD);
        const bf16x8 b0 = *(const bf16x8*)kh;
        const bf16x8 b1 = *(const bf16x8*)(kh + 32);
        const bf16x8 c0 = *(const bf16x8*)kl;
        const bf16x8 c1 = *(const bf16x8*)(kl + 32);
        f32x4 acc = (f32x4){0.f, 0.f, 0.f, 0.f};
        acc = __builtin_amdgcn_mfma_f32_16x16x32_bf16(qh0, b0, acc, 0, 0, 0);
        acc = __builtin_amdgcn_mfma_f32_16x16x32_bf16(qh1, b1, acc, 0, 0, 0);
        acc = __builtin_amdgcn_mfma_f32_16x16x32_bf16(ql0, b0, acc, 0, 0, 0);
        acc = __builtin_amdgcn_mfma_f32_16x16x32_bf16(ql1, b1, acc, 0, 0, 0);
        acc = __builtin_amdgcn_mfma_f32_16x16x32_bf16(qh0, c0, acc, 0, 0, 0);
        acc = __builtin_amdgcn_mfma_f32_16x16x32_bf16(qh1, c1, acc, 0, 0, 0);
#pragma unroll
        for (int r = 0; r < 4; ++r) z4[r] += __expf(acc[r]);
    }
#pragma unroll
    for (int m = 1; m < 16; m <<= 1) {
#pragma unroll
        for (int r = 0; r < 4; ++r) z4[r] += __shfl_xor(z4[r], m, 64);
    }
    if (lr == 0) {
#pragma unroll
        for (int r = 0; r < 4; ++r) atomicAdd(&ZB[rg * 16 + lg * 4 + r], z4[r]);
    }
    __syncthreads();
    float rz[4];
#pragma unroll
    for (int r = 0; r < 4; ++r) rz[r] = 1.0f / ZB[rg * 16 + lg * 4 + r];

    // ---- pass 2: weights + PV ----
    f32x4 accav = (f32x4){0.f, 0.f, 0.f, 0.f};
    const __bf16* vt_base = vt_ws + kvbase + (size_t)(cw * 16 + lr) * SS + lg * 8;
    float* wrow = wts + ((size_t)bh * SS + (i0 + rg * 16 + lg * 4)) * SS + cw * 16 + lr;
    int p = 0;
    for (int jt = 0; jt < 32; ++jt) {
        const int j0 = jt * 64;
        const __bf16* kh = kh_base + (size_t)jt * (64 * HD);
        const __bf16* kl = kl_base + (size_t)jt * (64 * HD);
        const bf16x8 b0 = *(const bf16x8*)kh;
        const bf16x8 b1 = *(const bf16x8*)(kh + 32);
        const bf16x8 c0 = *(const bf16x8*)kl;
        const bf16x8 c1 = *(const bf16x8*)(kl + 32);
        const bf16x8 vb0 = *(const bf16x8*)(vt_base + j0);
        const bf16x8 vb1 = *(const bf16x8*)(vt_base + j0 + 32);

        f32x4 acc = (f32x4){0.f, 0.f, 0.f, 0.f};
        acc = __builtin_amdgcn_mfma_f32_16x16x32_bf16(qh0, b0, acc, 0, 0, 0);
        acc = __builtin_amdgcn_mfma_f32_16x16x32_bf16(qh1, b1, acc, 0, 0, 0);
        acc = __builtin_amdgcn_mfma_f32_16x16x32_bf16(ql0, b0, acc, 0, 0, 0);
        acc = __builtin_amdgcn_mfma_f32_16x16x32_bf16(ql1, b1, acc, 0, 0, 0);
        acc = __builtin_amdgcn_mfma_f32_16x16x32_bf16(qh0, c0, acc, 0, 0, 0);
        acc = __builtin_amdgcn_mfma_f32_16x16x32_bf16(qh1, c1, acc, 0, 0, 0);

#pragma unroll
        for (int r = 0; r < 4; ++r) {
            const float w = __expf(acc[r]) * rz[r];
            wrow[(size_t)r * SS + j0] = w;                       // streamed weights
            UT[p][rg * 16 + lg * 4 + r][cw * 16 + lr] = (__bf16)w;
        }
        __syncthreads();
        const bf16x8 a0 = *(const bf16x8*)&UT[p][rg * 16 + lr][lg * 8];
        const bf16x8 a1 = *(const bf16x8*)&UT[p][rg * 16 + lr][32 + lg * 8];
        accav = __builtin_amdgcn_mfma_f32_16x16x32_bf16(a0, vb0, accav, 0, 0, 0);
        accav = __builtin_amdgcn_mfma_f32_16x16x32_bf16(a1, vb1, accav, 0, 0, 0);
        p ^= 1;
    }

    {   // av (already normalized) -> bf16 ws [B][S][E]
        const int b = bh >> 4, h = bh & 15;
#pragma unroll
        for (int r = 0; r < 4; ++r) {
            const int s = i0 + rg * 16 + lg * 4 + r;
            av_ws[((size_t)(b * SS + s)) * EE + h * HD + cw * 16 + lr] = (__bf16)accav[r];
        }
    }
}

// ---------------- K3: out projection (plain bf16) -------------------------
__global__ __launch_bounds__(256) void k_oproj(
    const __bf16* __restrict__ av_ws, const float* __restrict__ w_out,
    const float* __restrict__ b_out, float* __restrict__ out)
{
    __shared__ __bf16 Abf[128][72];
    __shared__ __bf16 Bbf[64][72];
    const int tid = threadIdx.x;
    const int lane = tid & 63;
    const int wv = tid >> 6;
    const int m0 = blockIdx.y * 128, f0 = blockIdx.x * 64;
    const int wr = (wv >> 1) * 64, wc = (wv & 1) * 32;
    const int lr = lane & 15, lg = lane >> 4;

    f32x4 acc[4][2];
#pragma unroll
    for (int a = 0; a < 4; ++a)
#pragma unroll
        for (int b = 0; b < 2; ++b) acc[a][b] = (f32x4){0.f, 0.f, 0.f, 0.f};

    for (int kt = 0; kt < 16; ++kt) {
        const int k0 = kt * 64;
        __syncthreads();
        {
            const int c = tid & 7, r0 = tid >> 3;
#pragma unroll
            for (int i = 0; i < 4; ++i) {
                const int row = r0 + i * 32;
                *(bf16x8*)&Abf[row][c * 8] =
                    *(const bf16x8*)(av_ws + (size_t)(m0 + row) * EE + k0 + c * 8);
            }
        }
        {
            const int c = tid & 15, r0 = tid >> 4;
#pragma unroll
            for (int i = 0; i < 4; ++i) {
                const int row = r0 + i * 16;
                const float4 v = *(const float4*)(w_out + (size_t)(f0 + row) * EE + k0 + c * 4);
                bf16x4 pk;
                pk[0] = (__bf16)v.x; pk[1] = (__bf16)v.y;
                pk[2] = (__bf16)v.z; pk[3] = (__bf16)v.w;
                *(bf16x4*)&Bbf[row][c * 4] = pk;
            }
        }
        __syncthreads();
#pragma unroll
        for (int ks = 0; ks < 2; ++ks) {
            const int koff = ks * 32 + lg * 8;
            bf16x8 a[4], b[2];
#pragma unroll
            for (int rt = 0; rt < 4; ++rt) a[rt] = *(const bf16x8*)&Abf[wr + rt * 16 + lr][koff];
#pragma unroll
            for (int ct = 0; ct < 2; ++ct) b[ct] = *(const bf16x8*)&Bbf[wc + ct * 16 + lr][koff];
#pragma unroll
            for (int rt = 0; rt < 4; ++rt)
#pragma unroll
                for (int ct = 0; ct < 2; ++ct)
                    acc[rt][ct] = __builtin_amdgcn_mfma_f32_16x16x32_bf16(a[rt], b[ct], acc[rt][ct], 0, 0, 0);
        }
    }
#pragma unroll
    for (int rt = 0; rt < 4; ++rt) {
        const int m = m0 + wr + rt * 16 + lg * 4;
#pragma unroll
        for (int ct = 0; ct < 2; ++ct) {
            const int f = f0 + wc + ct * 16 + lr;
            const float bo = b_out[f];
#pragma unroll
            for (int r = 0; r < 4; ++r)
                out[(size_t)(m + r) * EE + f] = acc[rt][ct][r] + bo;
        }
    }
}

extern "C" void kernel_launch(void* const* d_in, const int* in_sizes, int n_in,
                              void* d_out, int out_size, void* d_ws, size_t ws_size,
                              hipStream_t stream)
{
    const float* x    = (const float*)d_in[0];
    const float* wqkv = (const float*)d_in[1];
    const float* bqkv = (const float*)d_in[2];
    const float* wo   = (const float*)d_in[3];
    const float* bo   = (const float*)d_in[4];
    const float* rel  = (const float*)d_in[5];

    float* out = (float*)d_out;
    float* wts = out + (size_t)BB * SS * EE;      // weights region, written by K2

    const size_t NQ = (size_t)BB * HH * SS * HD;  // 4M elements
    __bf16* qhi_ws = (__bf16*)d_ws;               // 8 MB each
    __bf16* qlo_ws = qhi_ws + NQ;
    __bf16* khi_ws = qlo_ws + NQ;
    __bf16* klo_ws = khi_ws + NQ;
    __bf16* vt_ws  = klo_ws + NQ;
    __bf16* av_ws  = vt_ws + NQ;                  // ws total: 48 MB

    // hi/lo splits of x and w_qkv live in the weights output region:
    // fully consumed by K1 before K2 overwrites it. (28 MB of 512 MB.)
    __bf16* xhi = (__bf16*)wts;
    __bf16* xlo = xhi + (size_t)BB * SS * EE;
    __bf16* whi = xlo + (size_t)BB * SS * EE;
    __bf16* wlo = whi + (size_t)3 * EE * EE;

    k_split<<<dim3((BB * SS * EE) / 1024), 256, 0, stream>>>(x, xhi, xlo, (BB * SS * EE) / 4);
    k_split<<<dim3((3 * EE * EE) / 1024), 256, 0, stream>>>(wqkv, whi, wlo, (3 * EE * EE) / 4);
    k_qkv<<<dim3(48, 32), 256, 0, stream>>>(xhi, xlo, whi, wlo, bqkv, rel,
                                            qhi_ws, qlo_ws, khi_ws, klo_ws, vt_ws);
    k_attn2<<<dim3(BB * HH * (SS / 32)), 512, 0, stream>>>(qhi_ws, qlo_ws, khi_ws, klo_ws,
                                                           vt_ws, wts, av_ws);
    k_oproj<<<dim3(EE / 64, (BB * SS) / 128), 256, 0, stream>>>(av_ws, wo, bo, out);
}

// Round 3
// 479.751 us; speedup vs baseline: 1.5112x; 1.5112x over previous
//
#include <hip/hip_runtime.h>
#include <hip/hip_bf16.h>

#define BB 2
#define SS 2048
#define EE 1024
#define HH 16
#define HD 64

typedef __attribute__((ext_vector_type(8))) __bf16 bf16x8;
typedef __attribute__((ext_vector_type(4))) __bf16 bf16x4;
typedef __attribute__((ext_vector_type(4))) float f32x4;

__device__ __forceinline__ void split2(float x, __bf16& h, __bf16& l) {
    h = (__bf16)x;                 // RTNE
    l = (__bf16)(x - (float)h);    // residual
}

// ---------------- K0: elementwise fp32 -> bf16 hi/lo split ----------------
__global__ __launch_bounds__(256) void k_split(const float* __restrict__ in,
                                               __bf16* __restrict__ hi,
                                               __bf16* __restrict__ lo, int n4)
{
    int i = blockIdx.x * 256 + threadIdx.x;
    if (i >= n4) return;
    const float4 v = *(const float4*)(in + (size_t)i * 4);
    float t[4] = {v.x, v.y, v.z, v.w};
    bf16x4 h4, l4;
#pragma unroll
    for (int e = 0; e < 4; ++e) {
        __bf16 h, l; split2(t[e], h, l);
        h4[e] = h; l4[e] = l;
    }
    *(bf16x4*)(hi + (size_t)i * 4) = h4;
    *(bf16x4*)(lo + (size_t)i * 4) = l4;
}

// ---------------- K1: QKV projection (split-bf16 GEMM, fp32-accurate) -----
// q and k' are emitted PRE-SPLIT as bf16 hi/lo; k' = k/8 + rel.
// v is emitted transposed bf16 [BH][HD][S].
__global__ __launch_bounds__(256) void k_qkv(
    const __bf16* __restrict__ xhi, const __bf16* __restrict__ xlo,
    const __bf16* __restrict__ whi, const __bf16* __restrict__ wlo,
    const float* __restrict__ bqkv, const float* __restrict__ rel,
    __bf16* __restrict__ qhi_ws, __bf16* __restrict__ qlo_ws,
    __bf16* __restrict__ khi_ws, __bf16* __restrict__ klo_ws,
    __bf16* __restrict__ vt_ws)
{
    __shared__ __bf16 Ahi[128][72], Alo[128][72];
    __shared__ __bf16 Bhi[64][72],  Blo[64][72];

    const int tid = threadIdx.x;
    const int lane = tid & 63;
    const int wv = tid >> 6;
    const int m0 = blockIdx.y * 128;
    const int f0 = blockIdx.x * 64;
    const int wr = (wv >> 1) * 64, wc = (wv & 1) * 32;
    const int lr = lane & 15, lg = lane >> 4;

    f32x4 acc[4][2];
#pragma unroll
    for (int a = 0; a < 4; ++a)
#pragma unroll
        for (int b = 0; b < 2; ++b) acc[a][b] = (f32x4){0.f, 0.f, 0.f, 0.f};

    for (int kt = 0; kt < 16; ++kt) {
        const int k0 = kt * 64;
        __syncthreads();
        {   // stage A tile 128x64 (hi+lo)
            const int c = tid & 7, r0 = tid >> 3;
#pragma unroll
            for (int i = 0; i < 4; ++i) {
                const int row = r0 + i * 32;
                const size_t g = (size_t)(m0 + row) * EE + k0 + c * 8;
                *(bf16x8*)&Ahi[row][c * 8] = *(const bf16x8*)(xhi + g);
                *(bf16x8*)&Alo[row][c * 8] = *(const bf16x8*)(xlo + g);
            }
        }
        {   // stage B tile 64x64 (hi+lo)
            const int c = tid & 7, r0 = tid >> 3;
#pragma unroll
            for (int i = 0; i < 2; ++i) {
                const int row = r0 + i * 32;
                const size_t g = (size_t)(f0 + row) * EE + k0 + c * 8;
                *(bf16x8*)&Bhi[row][c * 8] = *(const bf16x8*)(whi + g);
                *(bf16x8*)&Blo[row][c * 8] = *(const bf16x8*)(wlo + g);
            }
        }
        __syncthreads();
#pragma unroll
        for (int ks = 0; ks < 2; ++ks) {
            const int koff = ks * 32 + lg * 8;
            bf16x8 ah[4], al[4], bh[2], bl[2];
#pragma unroll
            for (int rt = 0; rt < 4; ++rt) {
                ah[rt] = *(const bf16x8*)&Ahi[wr + rt * 16 + lr][koff];
                al[rt] = *(const bf16x8*)&Alo[wr + rt * 16 + lr][koff];
            }
#pragma unroll
            for (int ct = 0; ct < 2; ++ct) {
                bh[ct] = *(const bf16x8*)&Bhi[wc + ct * 16 + lr][koff];
                bl[ct] = *(const bf16x8*)&Blo[wc + ct * 16 + lr][koff];
            }
#pragma unroll
            for (int rt = 0; rt < 4; ++rt)
#pragma unroll
                for (int ct = 0; ct < 2; ++ct) {
                    acc[rt][ct] = __builtin_amdgcn_mfma_f32_16x16x32_bf16(ah[rt], bh[ct], acc[rt][ct], 0, 0, 0);
                    acc[rt][ct] = __builtin_amdgcn_mfma_f32_16x16x32_bf16(al[rt], bh[ct], acc[rt][ct], 0, 0, 0);
                    acc[rt][ct] = __builtin_amdgcn_mfma_f32_16x16x32_bf16(ah[rt], bl[ct], acc[rt][ct], 0, 0, 0);
                }
        }
    }

    // epilogue: tile's 64 f-cols are one (h, q/k/v) block since f0 % 64 == 0
    const int blk = f0 >> 6;             // 0..47
    const int h = blk / 3, typ = blk % 3;
#pragma unroll
    for (int rt = 0; rt < 4; ++rt) {
        const int m = m0 + wr + rt * 16 + lg * 4;
        const int b = m >> 11, s = m & 2047;
#pragma unroll
        for (int ct = 0; ct < 2; ++ct) {
            const int d = wc + ct * 16 + lr;
            const float bq = bqkv[f0 + d];
            if (typ == 0) {
                const size_t base = ((size_t)(b * HH + h) * SS + s) * HD + d;
#pragma unroll
                for (int r = 0; r < 4; ++r) {
                    __bf16 hh, ll; split2(acc[rt][ct][r] + bq, hh, ll);
                    qhi_ws[base + (size_t)r * HD] = hh;
                    qlo_ws[base + (size_t)r * HD] = ll;
                }
            } else if (typ == 1) {
                const size_t base = ((size_t)(b * HH + h) * SS + s) * HD + d;
                const size_t rb = ((size_t)h * SS + s) * HD + d;
#pragma unroll
                for (int r = 0; r < 4; ++r) {
                    const float t = (acc[rt][ct][r] + bq) * 0.125f + rel[rb + (size_t)r * HD];
                    __bf16 hh, ll; split2(t, hh, ll);
                    khi_ws[base + (size_t)r * HD] = hh;
                    klo_ws[base + (size_t)r * HD] = ll;
                }
            } else {
                const size_t base = ((size_t)(b * HH + h) * HD + d) * SS + s;
                bf16x4 pk;
#pragma unroll
                for (int r = 0; r < 4; ++r) pk[r] = (__bf16)(acc[rt][ct][r] + bq);
                *(bf16x4*)&vt_ws[base] = pk;
            }
        }
    }
}

// ---------------- K2: fused two-pass attention, barrier-free --------------
// 4 independent waves per block; each wave owns 32 q-rows and sweeps j in
// 64-col steps with 8 independent QK accumulator chains (48 MFMA/iter).
// Pass 1: Z via in-wave butterfly. Pass 2: P = exp*rz -> wave-private LDS
// tile (transpose for PV A-operand), PV accumulates, weights streamed as
// coalesced float4 stores from the P tile. No __syncthreads anywhere.
__global__ __launch_bounds__(256) void k_attn3(
    const __bf16* __restrict__ qhi_ws, const __bf16* __restrict__ qlo_ws,
    const __bf16* __restrict__ khi_ws, const __bf16* __restrict__ klo_ws,
    const __bf16* __restrict__ vt_ws,
    float* __restrict__ wts, __bf16* __restrict__ av_ws)
{
    __shared__ __bf16 P[4][32][72];   // wave-private P tiles (4.5 KB each)

    const int tid = threadIdx.x;
    const int lane = tid & 63;
    const int wv = tid >> 6;
    const int lr = lane & 15, lg = lane >> 4;

    // XCD-aware swizzle: 512 wgs, 64 per XCD -> 4 bh per XCD (K/V L2-resident)
    const int wgid = ((blockIdx.x & 7) << 6) | (blockIdx.x >> 3);
    const int bh = wgid >> 4;
    const int q0 = (wgid & 15) * 128 + wv * 32;
    const size_t kvb = (size_t)bh * SS * HD;

    // q fragments (hi/lo), 2 row-groups x 2 k-chunks
    bf16x8 qh[2][2], ql[2][2];
#pragma unroll
    for (int rg = 0; rg < 2; ++rg) {
        const size_t ro = kvb + (size_t)(q0 + rg * 16 + lr) * HD + lg * 8;
#pragma unroll
        for (int kk = 0; kk < 2; ++kk) {
            qh[rg][kk] = *(const bf16x8*)(qhi_ws + ro + kk * 32);
            ql[rg][kk] = *(const bf16x8*)(qlo_ws + ro + kk * 32);
        }
    }

    const __bf16* kh_base = khi_ws + kvb + (size_t)lr * HD + lg * 8;
    const __bf16* kl_base = klo_ws + kvb + (size_t)lr * HD + lg * 8;

    // ---- pass 1: Z ----
    float z[2][4] = {{0.f,0.f,0.f,0.f},{0.f,0.f,0.f,0.f}};
    for (int jt = 0; jt < 32; ++jt) {
        const size_t jo = (size_t)jt * (64 * HD);
        bf16x8 kh[4][2], kl[4][2];
#pragma unroll
        for (int cg = 0; cg < 4; ++cg) {
            const size_t co = jo + (size_t)cg * (16 * HD);
#pragma unroll
            for (int kk = 0; kk < 2; ++kk) {
                kh[cg][kk] = *(const bf16x8*)(kh_base + co + kk * 32);
                kl[cg][kk] = *(const bf16x8*)(kl_base + co + kk * 32);
            }
        }
        f32x4 a[2][4];
#pragma unroll
        for (int rg = 0; rg < 2; ++rg)
#pragma unroll
            for (int cg = 0; cg < 4; ++cg) {
                f32x4 t = (f32x4){0.f, 0.f, 0.f, 0.f};
                t = __builtin_amdgcn_mfma_f32_16x16x32_bf16(qh[rg][0], kh[cg][0], t, 0, 0, 0);
                t = __builtin_amdgcn_mfma_f32_16x16x32_bf16(qh[rg][1], kh[cg][1], t, 0, 0, 0);
                t = __builtin_amdgcn_mfma_f32_16x16x32_bf16(ql[rg][0], kh[cg][0], t, 0, 0, 0);
                t = __builtin_amdgcn_mfma_f32_16x16x32_bf16(ql[rg][1], kh[cg][1], t, 0, 0, 0);
                t = __builtin_amdgcn_mfma_f32_16x16x32_bf16(qh[rg][0], kl[cg][0], t, 0, 0, 0);
                t = __builtin_amdgcn_mfma_f32_16x16x32_bf16(qh[rg][1], kl[cg][1], t, 0, 0, 0);
                a[rg][cg] = t;
            }
#pragma unroll
        for (int rg = 0; rg < 2; ++rg)
#pragma unroll
            for (int cg = 0; cg < 4; ++cg)
#pragma unroll
                for (int r = 0; r < 4; ++r) z[rg][r] += __expf(a[rg][cg][r]);
    }
    // butterfly over the 16 lr lanes -> every lane holds Z for its rows
#pragma unroll
    for (int m = 1; m < 16; m <<= 1)
#pragma unroll
        for (int rg = 0; rg < 2; ++rg)
#pragma unroll
            for (int r = 0; r < 4; ++r) z[rg][r] += __shfl_xor(z[rg][r], m, 64);
    float rz[2][4];
#pragma unroll
    for (int rg = 0; rg < 2; ++rg)
#pragma unroll
        for (int r = 0; r < 4; ++r) rz[rg][r] = 1.0f / z[rg][r];

    // ---- pass 2: weights + PV ----
    f32x4 pv[2][4];
#pragma unroll
    for (int rg = 0; rg < 2; ++rg)
#pragma unroll
        for (int dg = 0; dg < 4; ++dg) pv[rg][dg] = (f32x4){0.f, 0.f, 0.f, 0.f};

    const __bf16* vt_base = vt_ws + kvb + (size_t)lr * SS + lg * 8;
    float* wbase = wts + ((size_t)bh * SS + q0) * SS;

    for (int jt = 0; jt < 32; ++jt) {
        const int j0 = jt * 64;
        const size_t jo = (size_t)jt * (64 * HD);
        bf16x8 kh[4][2], kl[4][2];
#pragma unroll
        for (int cg = 0; cg < 4; ++cg) {
            const size_t co = jo + (size_t)cg * (16 * HD);
#pragma unroll
            for (int kk = 0; kk < 2; ++kk) {
                kh[cg][kk] = *(const bf16x8*)(kh_base + co + kk * 32);
                kl[cg][kk] = *(const bf16x8*)(kl_base + co + kk * 32);
            }
        }
        f32x4 a[2][4];
#pragma unroll
        for (int rg = 0; rg < 2; ++rg)
#pragma unroll
            for (int cg = 0; cg < 4; ++cg) {
                f32x4 t = (f32x4){0.f, 0.f, 0.f, 0.f};
                t = __builtin_amdgcn_mfma_f32_16x16x32_bf16(qh[rg][0], kh[cg][0], t, 0, 0, 0);
                t = __builtin_amdgcn_mfma_f32_16x16x32_bf16(qh[rg][1], kh[cg][1], t, 0, 0, 0);
                t = __builtin_amdgcn_mfma_f32_16x16x32_bf16(ql[rg][0], kh[cg][0], t, 0, 0, 0);
                t = __builtin_amdgcn_mfma_f32_16x16x32_bf16(ql[rg][1], kh[cg][1], t, 0, 0, 0);
                t = __builtin_amdgcn_mfma_f32_16x16x32_bf16(qh[rg][0], kl[cg][0], t, 0, 0, 0);
                t = __builtin_amdgcn_mfma_f32_16x16x32_bf16(qh[rg][1], kl[cg][1], t, 0, 0, 0);
                a[rg][cg] = t;
            }
        // V fragments for this j-tile
        bf16x8 vb[4][2];
#pragma unroll
        for (int dg = 0; dg < 4; ++dg)
#pragma unroll
            for (int kk = 0; kk < 2; ++kk)
                vb[dg][kk] = *(const bf16x8*)(vt_base + (size_t)dg * (16 * SS) + j0 + kk * 32);
        // P = exp * rz -> wave-private LDS (transpose bounce)
#pragma unroll
        for (int rg = 0; rg < 2; ++rg)
#pragma unroll
            for (int cg = 0; cg < 4; ++cg)
#pragma unroll
                for (int r = 0; r < 4; ++r)
                    P[wv][rg * 16 + lg * 4 + r][cg * 16 + lr] =
                        (__bf16)(__expf(a[rg][cg][r]) * rz[rg][r]);
        // PV (A-frags from LDS; same-wave RAW handled by lgkmcnt)
#pragma unroll
        for (int rg = 0; rg < 2; ++rg) {
            bf16x8 pa0 = *(const bf16x8*)&P[wv][rg * 16 + lr][lg * 8];
            bf16x8 pa1 = *(const bf16x8*)&P[wv][rg * 16 + lr][32 + lg * 8];
#pragma unroll
            for (int dg = 0; dg < 4; ++dg) {
                pv[rg][dg] = __builtin_amdgcn_mfma_f32_16x16x32_bf16(pa0, vb[dg][0], pv[rg][dg], 0, 0, 0);
                pv[rg][dg] = __builtin_amdgcn_mfma_f32_16x16x32_bf16(pa1, vb[dg][1], pv[rg][dg], 0, 0, 0);
            }
        }
        // weights: coalesced float4 stores from the P tile (bf16-rounded)
#pragma unroll
        for (int it = 0; it < 8; ++it) {
            const int row = it * 4 + lg;
            const bf16x4 u = *(const bf16x4*)&P[wv][row][lr * 4];
            float4 o;
            o.x = (float)u[0]; o.y = (float)u[1]; o.z = (float)u[2]; o.w = (float)u[3];
            *(float4*)(wbase + (size_t)row * SS + j0 + lr * 4) = o;
        }
    }

    {   // av -> bf16 ws [B][S][E]
        const int b = bh >> 4, h = bh & 15;
#pragma unroll
        for (int rg = 0; rg < 2; ++rg)
#pragma unroll
            for (int dg = 0; dg < 4; ++dg)
#pragma unroll
                for (int r = 0; r < 4; ++r) {
                    const int s = q0 + rg * 16 + lg * 4 + r;
                    av_ws[((size_t)(b * SS + s)) * EE + h * HD + dg * 16 + lr] =
                        (__bf16)pv[rg][dg][r];
                }
    }
}

// ---------------- K3: out projection (plain bf16) -------------------------
__global__ __launch_bounds__(256) void k_oproj(
    const __bf16* __restrict__ av_ws, const float* __restrict__ w_out,
    const float* __restrict__ b_out, float* __restrict__ out)
{
    __shared__ __bf16 Abf[128][72];
    __shared__ __bf16 Bbf[64][72];
    const int tid = threadIdx.x;
    const int lane = tid & 63;
    const int wv = tid >> 6;
    const int m0 = blockIdx.y * 128, f0 = blockIdx.x * 64;
    const int wr = (wv >> 1) * 64, wc = (wv & 1) * 32;
    const int lr = lane & 15, lg = lane >> 4;

    f32x4 acc[4][2];
#pragma unroll
    for (int a = 0; a < 4; ++a)
#pragma unroll
        for (int b = 0; b < 2; ++b) acc[a][b] = (f32x4){0.f, 0.f, 0.f, 0.f};

    for (int kt = 0; kt < 16; ++kt) {
        const int k0 = kt * 64;
        __syncthreads();
        {
            const int c = tid & 7, r0 = tid >> 3;
#pragma unroll
            for (int i = 0; i < 4; ++i) {
                const int row = r0 + i * 32;
                *(bf16x8*)&Abf[row][c * 8] =
                    *(const bf16x8*)(av_ws + (size_t)(m0 + row) * EE + k0 + c * 8);
            }
        }
        {
            const int c = tid & 15, r0 = tid >> 4;
#pragma unroll
            for (int i = 0; i < 4; ++i) {
                const int row = r0 + i * 16;
                const float4 v = *(const float4*)(w_out + (size_t)(f0 + row) * EE + k0 + c * 4);
                bf16x4 pk;
                pk[0] = (__bf16)v.x; pk[1] = (__bf16)v.y;
                pk[2] = (__bf16)v.z; pk[3] = (__bf16)v.w;
                *(bf16x4*)&Bbf[row][c * 4] = pk;
            }
        }
        __syncthreads();
#pragma unroll
        for (int ks = 0; ks < 2; ++ks) {
            const int koff = ks * 32 + lg * 8;
            bf16x8 a[4], b[2];
#pragma unroll
            for (int rt = 0; rt < 4; ++rt) a[rt] = *(const bf16x8*)&Abf[wr + rt * 16 + lr][koff];
#pragma unroll
            for (int ct = 0; ct < 2; ++ct) b[ct] = *(const bf16x8*)&Bbf[wc + ct * 16 + lr][koff];
#pragma unroll
            for (int rt = 0; rt < 4; ++rt)
#pragma unroll
                for (int ct = 0; ct < 2; ++ct)
                    acc[rt][ct] = __builtin_amdgcn_mfma_f32_16x16x32_bf16(a[rt], b[ct], acc[rt][ct], 0, 0, 0);
        }
    }
#pragma unroll
    for (int rt = 0; rt < 4; ++rt) {
        const int m = m0 + wr + rt * 16 + lg * 4;
#pragma unroll
        for (int ct = 0; ct < 2; ++ct) {
            const int f = f0 + wc + ct * 16 + lr;
            const float bo = b_out[f];
#pragma unroll
            for (int r = 0; r < 4; ++r)
                out[(size_t)(m + r) * EE + f] = acc[rt][ct][r] + bo;
        }
    }
}

extern "C" void kernel_launch(void* const* d_in, const int* in_sizes, int n_in,
                              void* d_out, int out_size, void* d_ws, size_t ws_size,
                              hipStream_t stream)
{
    const float* x    = (const float*)d_in[0];
    const float* wqkv = (const float*)d_in[1];
    const float* bqkv = (const float*)d_in[2];
    const float* wo   = (const float*)d_in[3];
    const float* bo   = (const float*)d_in[4];
    const float* rel  = (const float*)d_in[5];

    float* out = (float*)d_out;
    float* wts = out + (size_t)BB * SS * EE;      // weights region, written by K2

    const size_t NQ = (size_t)BB * HH * SS * HD;  // 4M elements
    __bf16* qhi_ws = (__bf16*)d_ws;               // 8 MB each
    __bf16* qlo_ws = qhi_ws + NQ;
    __bf16* khi_ws = qlo_ws + NQ;
    __bf16* klo_ws = khi_ws + NQ;
    __bf16* vt_ws  = klo_ws + NQ;
    __bf16* av_ws  = vt_ws + NQ;                  // ws total: 48 MB

    // hi/lo splits of x and w_qkv live in the weights output region:
    // fully consumed by K1 before K2 overwrites it. (28 MB of 512 MB.)
    __bf16* xhi = (__bf16*)wts;
    __bf16* xlo = xhi + (size_t)BB * SS * EE;
    __bf16* whi = xlo + (size_t)BB * SS * EE;
    __bf16* wlo = whi + (size_t)3 * EE * EE;

    k_split<<<dim3((BB * SS * EE) / 1024), 256, 0, stream>>>(x, xhi, xlo, (BB * SS * EE) / 4);
    k_split<<<dim3((3 * EE * EE) / 1024), 256, 0, stream>>>(wqkv, whi, wlo, (3 * EE * EE) / 4);
    k_qkv<<<dim3(48, 32), 256, 0, stream>>>(xhi, xlo, whi, wlo, bqkv, rel,
                                            qhi_ws, qlo_ws, khi_ws, klo_ws, vt_ws);
    k_attn3<<<dim3(512), 256, 0, stream>>>(qhi_ws, qlo_ws, khi_ws, klo_ws,
                                           vt_ws, wts, av_ws);
    k_oproj<<<dim3(EE / 64, (BB * SS) / 128), 256, 0, stream>>>(av_ws, wo, bo, out);
}

// Round 4
// 476.832 us; speedup vs baseline: 1.5205x; 1.0061x over previous
//
#include <hip/hip_runtime.h>
#include <hip/hip_bf16.h>

#define BB 2
#define SS 2048
#define EE 1024
#define HH 16
#define HD 64

typedef __attribute__((ext_vector_type(8))) __bf16 bf16x8;
typedef __attribute__((ext_vector_type(4))) __bf16 bf16x4;
typedef __attribute__((ext_vector_type(4))) float f32x4;

__device__ __forceinline__ void split2(float x, __bf16& h, __bf16& l) {
    h = (__bf16)x;                 // RTNE
    l = (__bf16)(x - (float)h);    // residual
}

// ---------------- K0: elementwise fp32 -> bf16 hi/lo split ----------------
__global__ __launch_bounds__(256) void k_split(const float* __restrict__ in,
                                               __bf16* __restrict__ hi,
                                               __bf16* __restrict__ lo, int n4)
{
    int i = blockIdx.x * 256 + threadIdx.x;
    if (i >= n4) return;
    const float4 v = *(const float4*)(in + (size_t)i * 4);
    float t[4] = {v.x, v.y, v.z, v.w};
    bf16x4 h4, l4;
#pragma unroll
    for (int e = 0; e < 4; ++e) {
        __bf16 h, l; split2(t[e], h, l);
        h4[e] = h; l4[e] = l;
    }
    *(bf16x4*)(hi + (size_t)i * 4) = h4;
    *(bf16x4*)(lo + (size_t)i * 4) = l4;
}

// ---------------- K1: QKV projection (split-bf16 GEMM, fp32-accurate) -----
__global__ __launch_bounds__(256) void k_qkv(
    const __bf16* __restrict__ xhi, const __bf16* __restrict__ xlo,
    const __bf16* __restrict__ whi, const __bf16* __restrict__ wlo,
    const float* __restrict__ bqkv, const float* __restrict__ rel,
    __bf16* __restrict__ qhi_ws, __bf16* __restrict__ qlo_ws,
    __bf16* __restrict__ khi_ws, __bf16* __restrict__ klo_ws,
    __bf16* __restrict__ vt_ws)
{
    __shared__ __bf16 Ahi[128][72], Alo[128][72];
    __shared__ __bf16 Bhi[64][72],  Blo[64][72];

    const int tid = threadIdx.x;
    const int lane = tid & 63;
    const int wv = tid >> 6;
    const int m0 = blockIdx.y * 128;
    const int f0 = blockIdx.x * 64;
    const int wr = (wv >> 1) * 64, wc = (wv & 1) * 32;
    const int lr = lane & 15, lg = lane >> 4;

    f32x4 acc[4][2];
#pragma unroll
    for (int a = 0; a < 4; ++a)
#pragma unroll
        for (int b = 0; b < 2; ++b) acc[a][b] = (f32x4){0.f, 0.f, 0.f, 0.f};

    for (int kt = 0; kt < 16; ++kt) {
        const int k0 = kt * 64;
        __syncthreads();
        {   // stage A tile 128x64 (hi+lo)
            const int c = tid & 7, r0 = tid >> 3;
#pragma unroll
            for (int i = 0; i < 4; ++i) {
                const int row = r0 + i * 32;
                const size_t g = (size_t)(m0 + row) * EE + k0 + c * 8;
                *(bf16x8*)&Ahi[row][c * 8] = *(const bf16x8*)(xhi + g);
                *(bf16x8*)&Alo[row][c * 8] = *(const bf16x8*)(xlo + g);
            }
        }
        {   // stage B tile 64x64 (hi+lo)
            const int c = tid & 7, r0 = tid >> 3;
#pragma unroll
            for (int i = 0; i < 2; ++i) {
                const int row = r0 + i * 32;
                const size_t g = (size_t)(f0 + row) * EE + k0 + c * 8;
                *(bf16x8*)&Bhi[row][c * 8] = *(const bf16x8*)(whi + g);
                *(bf16x8*)&Blo[row][c * 8] = *(const bf16x8*)(wlo + g);
            }
        }
        __syncthreads();
#pragma unroll
        for (int ks = 0; ks < 2; ++ks) {
            const int koff = ks * 32 + lg * 8;
            bf16x8 ah[4], al[4], bh[2], bl[2];
#pragma unroll
            for (int rt = 0; rt < 4; ++rt) {
                ah[rt] = *(const bf16x8*)&Ahi[wr + rt * 16 + lr][koff];
                al[rt] = *(const bf16x8*)&Alo[wr + rt * 16 + lr][koff];
            }
#pragma unroll
            for (int ct = 0; ct < 2; ++ct) {
                bh[ct] = *(const bf16x8*)&Bhi[wc + ct * 16 + lr][koff];
                bl[ct] = *(const bf16x8*)&Blo[wc + ct * 16 + lr][koff];
            }
#pragma unroll
            for (int rt = 0; rt < 4; ++rt)
#pragma unroll
                for (int ct = 0; ct < 2; ++ct) {
                    acc[rt][ct] = __builtin_amdgcn_mfma_f32_16x16x32_bf16(ah[rt], bh[ct], acc[rt][ct], 0, 0, 0);
                    acc[rt][ct] = __builtin_amdgcn_mfma_f32_16x16x32_bf16(al[rt], bh[ct], acc[rt][ct], 0, 0, 0);
                    acc[rt][ct] = __builtin_amdgcn_mfma_f32_16x16x32_bf16(ah[rt], bl[ct], acc[rt][ct], 0, 0, 0);
                }
        }
    }

    const int blk = f0 >> 6;             // 0..47
    const int h = blk / 3, typ = blk % 3;
#pragma unroll
    for (int rt = 0; rt < 4; ++rt) {
        const int m = m0 + wr + rt * 16 + lg * 4;
        const int b = m >> 11, s = m & 2047;
#pragma unroll
        for (int ct = 0; ct < 2; ++ct) {
            const int d = wc + ct * 16 + lr;
            const float bq = bqkv[f0 + d];
            if (typ == 0) {
                const size_t base = ((size_t)(b * HH + h) * SS + s) * HD + d;
#pragma unroll
                for (int r = 0; r < 4; ++r) {
                    __bf16 hh, ll; split2(acc[rt][ct][r] + bq, hh, ll);
                    qhi_ws[base + (size_t)r * HD] = hh;
                    qlo_ws[base + (size_t)r * HD] = ll;
                }
            } else if (typ == 1) {
                const size_t base = ((size_t)(b * HH + h) * SS + s) * HD + d;
                const size_t rb = ((size_t)h * SS + s) * HD + d;
#pragma unroll
                for (int r = 0; r < 4; ++r) {
                    const float t = (acc[rt][ct][r] + bq) * 0.125f + rel[rb + (size_t)r * HD];
                    __bf16 hh, ll; split2(t, hh, ll);
                    khi_ws[base + (size_t)r * HD] = hh;
                    klo_ws[base + (size_t)r * HD] = ll;
                }
            } else {
                const size_t base = ((size_t)(b * HH + h) * HD + d) * SS + s;
                bf16x4 pk;
#pragma unroll
                for (int r = 0; r < 4; ++r) pk[r] = (__bf16)(acc[rt][ct][r] + bq);
                *(bf16x4*)&vt_ws[base] = pk;
            }
        }
    }
}

// ---------------- K2: fused two-pass attention, j-split 2-way -------------
// 4 waves/block own 64 q-rows: wave = (row-group rh, j-half jh). Each wave
// sweeps 16 j-tiles with 8 independent QK chains. Z partials exchanged via
// LDS (1 barrier); PV partials combined at the end through the reused P
// region (2 barriers). Grid 1024 -> 4 blocks/CU -> 16 waves/CU.
__global__ __launch_bounds__(256) void k_attn4(
    const __bf16* __restrict__ qhi_ws, const __bf16* __restrict__ qlo_ws,
    const __bf16* __restrict__ khi_ws, const __bf16* __restrict__ klo_ws,
    const __bf16* __restrict__ vt_ws,
    float* __restrict__ wts, __bf16* __restrict__ av_ws)
{
    __shared__ __bf16 P[4][32][72];   // wave-private P tiles; reused for PV combine
    __shared__ float ZX[4][32];       // Z partials exchange

    const int tid = threadIdx.x;
    const int lane = tid & 63;
    const int wv = tid >> 6;
    const int lr = lane & 15, lg = lane >> 4;
    const int rh = wv >> 1;           // row-half of the 64-row strip
    const int jh = wv & 1;            // j-half (each = 16 j-tiles = 1024 cols)

    // XCD chunked swizzle: 1024 wgs; each XCD gets 128 consecutive wgids
    // = 4 bh values -> K/V (~3 MB) resident in that XCD's L2.
    const int wgid = ((blockIdx.x & 7) << 7) | (blockIdx.x >> 3);
    const int bh = wgid >> 5;
    const int q0 = (wgid & 31) * 64 + rh * 32;
    const size_t kvb = (size_t)bh * SS * HD;

    // q fragments (hi/lo), 2 row-groups x 2 k-chunks
    bf16x8 qh[2][2], ql[2][2];
#pragma unroll
    for (int rg = 0; rg < 2; ++rg) {
        const size_t ro = kvb + (size_t)(q0 + rg * 16 + lr) * HD + lg * 8;
#pragma unroll
        for (int kk = 0; kk < 2; ++kk) {
            qh[rg][kk] = *(const bf16x8*)(qhi_ws + ro + kk * 32);
            ql[rg][kk] = *(const bf16x8*)(qlo_ws + ro + kk * 32);
        }
    }

    const __bf16* kh_base = khi_ws + kvb + (size_t)lr * HD + lg * 8;
    const __bf16* kl_base = klo_ws + kvb + (size_t)lr * HD + lg * 8;
    const int jt0 = jh * 16;

    // ---- pass 1: Z over this wave's j-half ----
    float z[2][4] = {{0.f,0.f,0.f,0.f},{0.f,0.f,0.f,0.f}};
#pragma unroll 2
    for (int t = 0; t < 16; ++t) {
        const size_t jo = (size_t)(jt0 + t) * (64 * HD);
        bf16x8 kh[4][2], kl[4][2];
#pragma unroll
        for (int cg = 0; cg < 4; ++cg) {
            const size_t co = jo + (size_t)cg * (16 * HD);
#pragma unroll
            for (int kk = 0; kk < 2; ++kk) {
                kh[cg][kk] = *(const bf16x8*)(kh_base + co + kk * 32);
                kl[cg][kk] = *(const bf16x8*)(kl_base + co + kk * 32);
            }
        }
        f32x4 a[2][4];
#pragma unroll
        for (int rg = 0; rg < 2; ++rg)
#pragma unroll
            for (int cg = 0; cg < 4; ++cg) {
                f32x4 u = (f32x4){0.f, 0.f, 0.f, 0.f};
                u = __builtin_amdgcn_mfma_f32_16x16x32_bf16(qh[rg][0], kh[cg][0], u, 0, 0, 0);
                u = __builtin_amdgcn_mfma_f32_16x16x32_bf16(qh[rg][1], kh[cg][1], u, 0, 0, 0);
                u = __builtin_amdgcn_mfma_f32_16x16x32_bf16(ql[rg][0], kh[cg][0], u, 0, 0, 0);
                u = __builtin_amdgcn_mfma_f32_16x16x32_bf16(ql[rg][1], kh[cg][1], u, 0, 0, 0);
                u = __builtin_amdgcn_mfma_f32_16x16x32_bf16(qh[rg][0], kl[cg][0], u, 0, 0, 0);
                u = __builtin_amdgcn_mfma_f32_16x16x32_bf16(qh[rg][1], kl[cg][1], u, 0, 0, 0);
                a[rg][cg] = u;
            }
#pragma unroll
        for (int rg = 0; rg < 2; ++rg)
#pragma unroll
            for (int cg = 0; cg < 4; ++cg)
#pragma unroll
                for (int r = 0; r < 4; ++r) z[rg][r] += __expf(a[rg][cg][r]);
    }
    // butterfly over the 16 lr lanes
#pragma unroll
    for (int m = 1; m < 16; m <<= 1)
#pragma unroll
        for (int rg = 0; rg < 2; ++rg)
#pragma unroll
            for (int r = 0; r < 4; ++r) z[rg][r] += __shfl_xor(z[rg][r], m, 64);
    // exchange partial Z with the partner wave (other j-half)
    if (lr == 0) {
#pragma unroll
        for (int rg = 0; rg < 2; ++rg)
#pragma unroll
            for (int r = 0; r < 4; ++r) ZX[wv][rg * 16 + lg * 4 + r] = z[rg][r];
    }
    __syncthreads();
    float rz[2][4];
#pragma unroll
    for (int rg = 0; rg < 2; ++rg)
#pragma unroll
        for (int r = 0; r < 4; ++r)
            rz[rg][r] = 1.0f / (z[rg][r] + ZX[wv ^ 1][rg * 16 + lg * 4 + r]);

    // ---- pass 2: weights + PV over this wave's j-half ----
    f32x4 pv[2][4];
#pragma unroll
    for (int rg = 0; rg < 2; ++rg)
#pragma unroll
        for (int dg = 0; dg < 4; ++dg) pv[rg][dg] = (f32x4){0.f, 0.f, 0.f, 0.f};

    const __bf16* vt_base = vt_ws + kvb + (size_t)lr * SS + lg * 8;
    float* wbase = wts + ((size_t)bh * SS + q0) * SS;

    for (int t = 0; t < 16; ++t) {
        const int jt = jt0 + t;
        const int j0 = jt * 64;
        const size_t jo = (size_t)jt * (64 * HD);
        bf16x8 kh[4][2], kl[4][2];
#pragma unroll
        for (int cg = 0; cg < 4; ++cg) {
            const size_t co = jo + (size_t)cg * (16 * HD);
#pragma unroll
            for (int kk = 0; kk < 2; ++kk) {
                kh[cg][kk] = *(const bf16x8*)(kh_base + co + kk * 32);
                kl[cg][kk] = *(const bf16x8*)(kl_base + co + kk * 32);
            }
        }
        f32x4 a[2][4];
#pragma unroll
        for (int rg = 0; rg < 2; ++rg)
#pragma unroll
            for (int cg = 0; cg < 4; ++cg) {
                f32x4 u = (f32x4){0.f, 0.f, 0.f, 0.f};
                u = __builtin_amdgcn_mfma_f32_16x16x32_bf16(qh[rg][0], kh[cg][0], u, 0, 0, 0);
                u = __builtin_amdgcn_mfma_f32_16x16x32_bf16(qh[rg][1], kh[cg][1], u, 0, 0, 0);
                u = __builtin_amdgcn_mfma_f32_16x16x32_bf16(ql[rg][0], kh[cg][0], u, 0, 0, 0);
                u = __builtin_amdgcn_mfma_f32_16x16x32_bf16(ql[rg][1], kh[cg][1], u, 0, 0, 0);
                u = __builtin_amdgcn_mfma_f32_16x16x32_bf16(qh[rg][0], kl[cg][0], u, 0, 0, 0);
                u = __builtin_amdgcn_mfma_f32_16x16x32_bf16(qh[rg][1], kl[cg][1], u, 0, 0, 0);
                a[rg][cg] = u;
            }
        bf16x8 vb[4][2];
#pragma unroll
        for (int dg = 0; dg < 4; ++dg)
#pragma unroll
            for (int kk = 0; kk < 2; ++kk)
                vb[dg][kk] = *(const bf16x8*)(vt_base + (size_t)dg * (16 * SS) + j0 + kk * 32);
        // P = exp * rz -> wave-private LDS (transpose bounce)
#pragma unroll
        for (int rg = 0; rg < 2; ++rg)
#pragma unroll
            for (int cg = 0; cg < 4; ++cg)
#pragma unroll
                for (int r = 0; r < 4; ++r)
                    P[wv][rg * 16 + lg * 4 + r][cg * 16 + lr] =
                        (__bf16)(__expf(a[rg][cg][r]) * rz[rg][r]);
#pragma unroll
        for (int rg = 0; rg < 2; ++rg) {
            bf16x8 pa0 = *(const bf16x8*)&P[wv][rg * 16 + lr][lg * 8];
            bf16x8 pa1 = *(const bf16x8*)&P[wv][rg * 16 + lr][32 + lg * 8];
#pragma unroll
            for (int dg = 0; dg < 4; ++dg) {
                pv[rg][dg] = __builtin_amdgcn_mfma_f32_16x16x32_bf16(pa0, vb[dg][0], pv[rg][dg], 0, 0, 0);
                pv[rg][dg] = __builtin_amdgcn_mfma_f32_16x16x32_bf16(pa1, vb[dg][1], pv[rg][dg], 0, 0, 0);
            }
        }
        // weights: coalesced float4 stores from the P tile (bf16-rounded)
#pragma unroll
        for (int it = 0; it < 8; ++it) {
            const int row = it * 4 + lg;
            const bf16x4 u = *(const bf16x4*)&P[wv][row][lr * 4];
            float4 o;
            o.x = (float)u[0]; o.y = (float)u[1]; o.z = (float)u[2]; o.w = (float)u[3];
            *(float4*)(wbase + (size_t)row * SS + j0 + lr * 4) = o;
        }
    }

    // ---- combine PV partials across j-halves (reuse P region as f32) ----
    __syncthreads();                      // all waves done with their P tiles
    float* X = (float*)&P[0][0][0];       // 2 pairs x 32x64 f32 = 16 KB
    if (jh == 1) {
#pragma unroll
        for (int rg = 0; rg < 2; ++rg)
#pragma unroll
            for (int dg = 0; dg < 4; ++dg)
#pragma unroll
                for (int r = 0; r < 4; ++r)
                    X[rh * 2048 + (rg * 16 + lg * 4 + r) * 64 + dg * 16 + lr] = pv[rg][dg][r];
    }
    __syncthreads();
    if (jh == 0) {
        const int b = bh >> 4, h = bh & 15;
#pragma unroll
        for (int rg = 0; rg < 2; ++rg)
#pragma unroll
            for (int dg = 0; dg < 4; ++dg)
#pragma unroll
                for (int r = 0; r < 4; ++r) {
                    const float av = pv[rg][dg][r] +
                        X[rh * 2048 + (rg * 16 + lg * 4 + r) * 64 + dg * 16 + lr];
                    const int s = q0 + rg * 16 + lg * 4 + r;
                    av_ws[((size_t)(b * SS + s)) * EE + h * HD + dg * 16 + lr] = (__bf16)av;
                }
    }
}

// ---------------- K3: out projection (plain bf16) -------------------------
__global__ __launch_bounds__(256) void k_oproj(
    const __bf16* __restrict__ av_ws, const float* __restrict__ w_out,
    const float* __restrict__ b_out, float* __restrict__ out)
{
    __shared__ __bf16 Abf[128][72];
    __shared__ __bf16 Bbf[64][72];
    const int tid = threadIdx.x;
    const int lane = tid & 63;
    const int wv = tid >> 6;
    const int m0 = blockIdx.y * 128, f0 = blockIdx.x * 64;
    const int wr = (wv >> 1) * 64, wc = (wv & 1) * 32;
    const int lr = lane & 15, lg = lane >> 4;

    f32x4 acc[4][2];
#pragma unroll
    for (int a = 0; a < 4; ++a)
#pragma unroll
        for (int b = 0; b < 2; ++b) acc[a][b] = (f32x4){0.f, 0.f, 0.f, 0.f};

    for (int kt = 0; kt < 16; ++kt) {
        const int k0 = kt * 64;
        __syncthreads();
        {
            const int c = tid & 7, r0 = tid >> 3;
#pragma unroll
            for (int i = 0; i < 4; ++i) {
                const int row = r0 + i * 32;
                *(bf16x8*)&Abf[row][c * 8] =
                    *(const bf16x8*)(av_ws + (size_t)(m0 + row) * EE + k0 + c * 8);
            }
        }
        {
            const int c = tid & 15, r0 = tid >> 4;
#pragma unroll
            for (int i = 0; i < 4; ++i) {
                const int row = r0 + i * 16;
                const float4 v = *(const float4*)(w_out + (size_t)(f0 + row) * EE + k0 + c * 4);
                bf16x4 pk;
                pk[0] = (__bf16)v.x; pk[1] = (__bf16)v.y;
                pk[2] = (__bf16)v.z; pk[3] = (__bf16)v.w;
                *(bf16x4*)&Bbf[row][c * 4] = pk;
            }
        }
        __syncthreads();
#pragma unroll
        for (int ks = 0; ks < 2; ++ks) {
            const int koff = ks * 32 + lg * 8;
            bf16x8 a[4], b[2];
#pragma unroll
            for (int rt = 0; rt < 4; ++rt) a[rt] = *(const bf16x8*)&Abf[wr + rt * 16 + lr][koff];
#pragma unroll
            for (int ct = 0; ct < 2; ++ct) b[ct] = *(const bf16x8*)&Bbf[wc + ct * 16 + lr][koff];
#pragma unroll
            for (int rt = 0; rt < 4; ++rt)
#pragma unroll
                for (int ct = 0; ct < 2; ++ct)
                    acc[rt][ct] = __builtin_amdgcn_mfma_f32_16x16x32_bf16(a[rt], b[ct], acc[rt][ct], 0, 0, 0);
        }
    }
#pragma unroll
    for (int rt = 0; rt < 4; ++rt) {
        const int m = m0 + wr + rt * 16 + lg * 4;
#pragma unroll
        for (int ct = 0; ct < 2; ++ct) {
            const int f = f0 + wc + ct * 16 + lr;
            const float bo = b_out[f];
#pragma unroll
            for (int r = 0; r < 4; ++r)
                out[(size_t)(m + r) * EE + f] = acc[rt][ct][r] + bo;
        }
    }
}

extern "C" void kernel_launch(void* const* d_in, const int* in_sizes, int n_in,
                              void* d_out, int out_size, void* d_ws, size_t ws_size,
                              hipStream_t stream)
{
    const float* x    = (const float*)d_in[0];
    const float* wqkv = (const float*)d_in[1];
    const float* bqkv = (const float*)d_in[2];
    const float* wo   = (const float*)d_in[3];
    const float* bo   = (const float*)d_in[4];
    const float* rel  = (const float*)d_in[5];

    float* out = (float*)d_out;
    float* wts = out + (size_t)BB * SS * EE;      // weights region, written by K2

    const size_t NQ = (size_t)BB * HH * SS * HD;  // 4M elements
    __bf16* qhi_ws = (__bf16*)d_ws;               // 8 MB each
    __bf16* qlo_ws = qhi_ws + NQ;
    __bf16* khi_ws = qlo_ws + NQ;
    __bf16* klo_ws = khi_ws + NQ;
    __bf16* vt_ws  = klo_ws + NQ;
    __bf16* av_ws  = vt_ws + NQ;                  // ws total: 48 MB

    // hi/lo splits of x and w_qkv live in the weights output region:
    // fully consumed by K1 before K2 overwrites it. (28 MB of 512 MB.)
    __bf16* xhi = (__bf16*)wts;
    __bf16* xlo = xhi + (size_t)BB * SS * EE;
    __bf16* whi = xlo + (size_t)BB * SS * EE;
    __bf16* wlo = whi + (size_t)3 * EE * EE;

    k_split<<<dim3((BB * SS * EE) / 1024), 256, 0, stream>>>(x, xhi, xlo, (BB * SS * EE) / 4);
    k_split<<<dim3((3 * EE * EE) / 1024), 256, 0, stream>>>(wqkv, whi, wlo, (3 * EE * EE) / 4);
    k_qkv<<<dim3(48, 32), 256, 0, stream>>>(xhi, xlo, whi, wlo, bqkv, rel,
                                            qhi_ws, qlo_ws, khi_ws, klo_ws, vt_ws);
    k_attn4<<<dim3(1024), 256, 0, stream>>>(qhi_ws, qlo_ws, khi_ws, klo_ws,
                                            vt_ws, wts, av_ws);
    k_oproj<<<dim3(EE / 64, (BB * SS) / 128), 256, 0, stream>>>(av_ws, wo, bo, out);
}